// Round 12
// baseline (22289.372 us; speedup 1.0000x reference)
//
#include <hip/hip_runtime.h>

#define TT 2048
#define BB 32
#define DD 512
#define HH 512
#define NWGS 16          // scan workgroups (32 units each)
#define STHR 1024        // scan threads per WG (16 waves)
#define NTHR 256

typedef short s8v __attribute__((ext_vector_type(8)));
typedef float f4v __attribute__((ext_vector_type(4)));
typedef unsigned u4v __attribute__((ext_vector_type(4)));

union UF { u4v u; s8v s; };

__device__ __forceinline__ float asf(unsigned u) { return __uint_as_float(u); }

// v_cvt_pk_bf16_f32: D[15:0]=bf16(a) RNE, D[31:16]=bf16(b)
__device__ __forceinline__ unsigned cvtpk(float a, float b) {
    unsigned r;
    asm("v_cvt_pk_bf16_f32 %0, %1, %2" : "=v"(r) : "v"(a), "v"(b));
    return r;
}
__device__ __forceinline__ void split2(float a, float b, unsigned& hp, unsigned& lp) {
    hp = cvtpk(a, b);
    lp = cvtpk(a - asf(hp << 16), b - asf(hp & 0xFFFF0000u));
}

// ws (bytes): [0) hhi 2x32KB | [64K) cbuf 64K | [128K) flags 4K | [132K) xg chunk
__global__ void lstm_init(const float* __restrict__ h0, const float* __restrict__ c0,
                          unsigned* __restrict__ hhi, float* __restrict__ cbuf,
                          unsigned* __restrict__ flags) {
    int j = blockIdx.x * blockDim.x + threadIdx.x;   // 0..16383
    if (j < NWGS * 16) flags[j] = 0u;
    if (j < BB * HH / 2) hhi[j] = cvtpk(h0[2 * j], h0[2 * j + 1]);
    cbuf[j] = c0[j];
}

// Phase 1: xg[i][batch32][2048] = x_t @ Wx + bias  (hi/lo exact-ish), i = t - t0
__global__ __launch_bounds__(NTHR) void gemm_xg(
    const float* __restrict__ x, const float* __restrict__ W,
    const float* __restrict__ bias, float* __restrict__ xg, int t0)
{
    const int wg8 = blockIdx.x & 63;     // unit octet
    const int tcb = blockIdx.x >> 6;     // 64-step block
    const int tid = threadIdx.x;
    const int u0  = wg8 * 8;
    const int wv  = tid >> 6, ln = tid & 63;
    const int bh  = wv >> 1, ch = wv & 1;
    const int fl  = ln & 15, fg = ln >> 4;

    s8v whi[16], wlo[16];
    const int col32 = ch * 16 + fl;
    const int gcol  = ((col32 >> 3) << 9) + u0 + (col32 & 7);  // gate*512 + unit
    #pragma unroll
    for (int it = 0; it < 16; ++it) {
        float v[8];
        #pragma unroll
        for (int j = 0; j < 8; ++j)
            v[j] = W[(size_t)(it * 32 + fg * 8 + j) * 2048 + gcol];
        UF H, L;
        #pragma unroll
        for (int q = 0; q < 4; ++q) {
            unsigned hp, lp;
            split2(v[2 * q], v[2 * q + 1], hp, lp);
            H.u[q] = hp; L.u[q] = lp;
        }
        whi[it] = H.s; wlo[it] = L.s;
    }
    const float bcol = bias[gcol];

    const int arow = bh * 16 + fl;
    const float* xlane = x + (size_t)arow * TT * DD + fg * 8;

    for (int ii = 0; ii < 64; ++ii) {
        const int i = tcb * 64 + ii;
        const int t = t0 + i;
        f4v acc  = {0.f, 0.f, 0.f, 0.f};
        f4v accl = {0.f, 0.f, 0.f, 0.f};
        const float* xs = xlane + (size_t)t * DD;
        #pragma unroll
        for (int it = 0; it < 16; ++it) {
            float4 f0 = *(const float4*)(xs + it * 32);
            float4 f1 = *(const float4*)(xs + it * 32 + 4);
            UF H, L;
            unsigned hp, lp;
            split2(f0.x, f0.y, hp, lp); H.u[0] = hp; L.u[0] = lp;
            split2(f0.z, f0.w, hp, lp); H.u[1] = hp; L.u[1] = lp;
            split2(f1.x, f1.y, hp, lp); H.u[2] = hp; L.u[2] = lp;
            split2(f1.z, f1.w, hp, lp); H.u[3] = hp; L.u[3] = lp;
            acc  = __builtin_amdgcn_mfma_f32_16x16x32_bf16(H.s, whi[it], acc, 0, 0, 0);
            accl = __builtin_amdgcn_mfma_f32_16x16x32_bf16(L.s, whi[it], accl, 0, 0, 0);
            accl = __builtin_amdgcn_mfma_f32_16x16x32_bf16(H.s, wlo[it], accl, 0, 0, 0);
        }
        float* dst = xg + (size_t)i * (BB * 2048);
        #pragma unroll
        for (int r = 0; r < 4; ++r)
            dst[(size_t)(bh * 16 + fg * 4 + r) * 2048 + gcol] = acc[r] + accl[r] + bcol;
    }
}

// Phase 2: persistent scan, 16 WGs x 1024 thr; h & Wh as bf16-hi only
__global__ __launch_bounds__(STHR, 1) void lstm_scan(
    const float* __restrict__ W,     // rows 512..1023 = Wh
    const float* __restrict__ xg,    // chunk-local [i][32][2048]
    float* __restrict__ out,
    unsigned* hhi,                   // cross-WG shared, packed bf16 pairs
    float* __restrict__ cbuf,
    unsigned* flags, int t0, int nt)
{
    __shared__ float P[32][132];     // [batch][col128], pad->bank-spread

    const int wg  = blockIdx.x;      // 0..15, owns units u0..u0+31
    const int tid = threadIdx.x;     // 0..1023
    const int u0  = wg * 32;
    const int wv  = tid >> 6, ln = tid & 63;
    const int bh  = wv & 1;          // batch half
    const int cq  = wv >> 1;         // col-16 tile (0..7)
    const int fl  = ln & 15, fg = ln >> 4;

    // Wh slice -> registers, bf16 hi only (64 VGPR/lane)
    s8v whi[16];
    {
        const int wcol = (cq >> 1) * 512 + u0 + (cq & 1) * 16 + fl;  // gate*512+unit
        #pragma unroll
        for (int it = 0; it < 16; ++it) {
            UF H;
            #pragma unroll
            for (int q = 0; q < 4; ++q) {
                float a = W[(size_t)(512 + it * 32 + fg * 8 + 2 * q) * 2048 + wcol];
                float b = W[(size_t)(512 + it * 32 + fg * 8 + 2 * q + 1) * 2048 + wcol];
                H.u[q] = cvtpk(a, b);
            }
            whi[it] = H.s;
        }
    }

    const int em = tid >> 5, ei = tid & 31;    // cell ownership: (batch, unit u0+ei)
    float cst = cbuf[em * HH + u0 + ei];

    const int arow = bh * 16 + fl;
    const int hb   = arow * 256;               // u32 row base in h buffer

    for (int i = 0; i < nt; ++i) {
        const int t = t0 + i;

        // xg loads first (no h dependency; hidden under the poll)
        const float* xs = xg + (size_t)i * (BB * 2048) + em * 2048 + u0 + ei;
        float xgi = xs[0], xgf = xs[512], xgg = xs[1024], xgo = xs[1536];

        if (t > 0) {
            if (tid < 64) {
                for (;;) {
                    unsigned v = (tid < NWGS)
                        ? __hip_atomic_load(&flags[tid * 16], __ATOMIC_RELAXED,
                                            __HIP_MEMORY_SCOPE_AGENT)
                        : (unsigned)t;
                    if (__all((int)v >= t)) break;
                }
            }
            __syncthreads();
            __builtin_amdgcn_fence(__ATOMIC_ACQUIRE, "agent");
        }

        // h contribution: 16 MFMA per wave (bf16 hi x hi)
        f4v acc = {0.f, 0.f, 0.f, 0.f};
        {
            const unsigned* hh = hhi + (size_t)(t & 1) * (BB * HH / 2);
            #pragma unroll
            for (int it = 0; it < 16; ++it) {
                UF H;
                H.u = *(const u4v*)(hh + hb + it * 16 + fg * 4);
                acc = __builtin_amdgcn_mfma_f32_16x16x32_bf16(H.s, whi[it], acc, 0, 0, 0);
            }
        }
        #pragma unroll
        for (int r = 0; r < 4; ++r)
            P[bh * 16 + fg * 4 + r][cq * 16 + fl] = acc[r];
        __syncthreads();

        // cell
        float gi = xgi + P[em][ei];
        float gf = xgf + P[em][32 + ei];
        float gg = xgg + P[em][64 + ei];
        float go = xgo + P[em][96 + ei];
        float si = 1.0f / (1.0f + __expf(-gi));
        float sf = 1.0f / (1.0f + __expf(-gf));
        float e2 = __expf(2.0f * fminf(fmaxf(gg, -15.f), 15.f));
        float tg = (e2 - 1.0f) / (e2 + 1.0f);
        float so = 1.0f / (1.0f + __expf(-go));
        cst = sf * cst + si * tg;
        float e2c = __expf(2.0f * fminf(fmaxf(cst, -15.f), 15.f));
        float h = so * (e2c - 1.0f) / (e2c + 1.0f);

        // publish h_{t+1} (packed bf16 pairs)
        {
            float hn = __shfl_down(h, 1);
            if ((ei & 1) == 0) {
                unsigned hp = cvtpk(h, hn);
                unsigned* dh = hhi + (size_t)((t + 1) & 1) * (BB * HH / 2);
                __hip_atomic_store(&dh[em * 256 + ((u0 + ei) >> 1)], hp,
                                   __ATOMIC_RELAXED, __HIP_MEMORY_SCOPE_AGENT);
            }
        }
        __syncthreads();   // vmcnt(0) drain: h stores committed before flag
        if (tid == 0)
            __hip_atomic_store(&flags[wg * 16], (unsigned)(t + 1),
                               __ATOMIC_RELAXED, __HIP_MEMORY_SCOPE_AGENT);

        // outputs off the critical path
        out[(size_t)em * TT * HH + (size_t)t * HH + u0 + ei] = h;
        if (t == TT - 1) {
            size_t ho = (size_t)BB * TT * HH;
            out[ho + em * HH + u0 + ei] = h;
            out[ho + (size_t)BB * HH + em * HH + u0 + ei] = cst;
        }
    }

    cbuf[em * HH + u0 + ei] = cst;   // checkpoint c for next chunk
}

extern "C" void kernel_launch(void* const* d_in, const int* in_sizes, int n_in,
                              void* d_out, int out_size, void* d_ws, size_t ws_size,
                              hipStream_t stream) {
    const float* x  = nullptr;
    const float* W  = nullptr;
    const float* b  = nullptr;
    const float* h0 = nullptr;
    const float* c0 = nullptr;
    for (int i = 0; i < n_in; ++i) {
        int sz = in_sizes[i];
        if      (sz == BB * TT * DD)       x = (const float*)d_in[i];
        else if (sz == (DD + HH) * 4 * HH) W = (const float*)d_in[i];
        else if (sz == 4 * HH)             b = (const float*)d_in[i];
        else if (sz == BB * HH) { if (!h0) h0 = (const float*)d_in[i];
                                  else     c0 = (const float*)d_in[i]; }
    }
    float* out = (float*)d_out;

    char* base = (char*)d_ws;
    unsigned* hhi   = (unsigned*)(base);            // 2 x 8192 u32 = 64 KB
    float*    cbuf  = (float*)   (base + 65536);    // 64 KB
    unsigned* flags = (unsigned*)(base + 131072);   // 4 KB
    float*    xg    = (float*)   (base + 135168);

    size_t avail = (ws_size > 135168) ? ws_size - 135168 : 0;
    size_t maxT  = avail / (BB * 2048 * sizeof(float));   // 262144 B per step
    int Tc = (int)((maxT / 64) * 64);
    if (Tc > TT) Tc = TT;
    if (Tc < 64) Tc = 64;

    lstm_init<<<64, NTHR, 0, stream>>>(h0, c0, hhi, cbuf, flags);

    for (int t0 = 0; t0 < TT; t0 += Tc) {
        int nt = (TT - t0 < Tc) ? (TT - t0) : Tc;
        gemm_xg<<<(nt / 64) * 64, NTHR, 0, stream>>>(x, W, b, xg, t0);
        lstm_scan<<<NWGS, STHR, 0, stream>>>(W, xg, out, hhi, cbuf, flags, t0, nt);
    }
}

// Round 13
// 20193.617 us; speedup vs baseline: 1.1038x; 1.1038x over previous
//
#include <hip/hip_runtime.h>

#define TT 2048
#define BB 32
#define DD 512
#define HH 512
#define NWG 64
#define NTHR 256

typedef short s8v __attribute__((ext_vector_type(8)));
typedef float f4v __attribute__((ext_vector_type(4)));
typedef unsigned u4v __attribute__((ext_vector_type(4)));
typedef unsigned long long u64;

union UF { u4v u; s8v s; };

__device__ __forceinline__ float asf(unsigned u) { return __uint_as_float(u); }

// v_cvt_pk_bf16_f32: D[15:0]=bf16(a) RNE, D[31:16]=bf16(b)
__device__ __forceinline__ unsigned cvtpk(float a, float b) {
    unsigned r;
    asm("v_cvt_pk_bf16_f32 %0, %1, %2" : "=v"(r) : "v"(a), "v"(b));
    return r;
}
__device__ __forceinline__ void split2(float a, float b, unsigned& hp, unsigned& lp) {
    hp = cvtpk(a, b);
    lp = cvtpk(a - asf(hp << 16), b - asf(hp & 0xFFFF0000u));
}

// ws (bytes): [0) hhi 2x32KB | [64K) cbuf 64K | [128K) flags 1K(+pad 4K) | [132K) xg chunk
__global__ void lstm_init(const float* __restrict__ h0, const float* __restrict__ c0,
                          unsigned* __restrict__ hhi, float* __restrict__ cbuf,
                          unsigned* __restrict__ flags) {
    int j = blockIdx.x * blockDim.x + threadIdx.x;   // 0..16383
    if (j < NWG * 4) flags[j] = 0u;                  // one flag per wave
    if (j < BB * HH / 2) hhi[j] = cvtpk(h0[2 * j], h0[2 * j + 1]);
    cbuf[j] = c0[j];
}

// Phase 1: xg[i][gatecol 2048][batch 32] = (x_t @ Wx + bias)^T   (hi/lo split GEMM)
__global__ __launch_bounds__(NTHR) void gemm_xg(
    const float* __restrict__ x, const float* __restrict__ W,
    const float* __restrict__ bias, float* __restrict__ xg, int t0)
{
    const int wg8 = blockIdx.x & 63;
    const int tcb = blockIdx.x >> 6;
    const int tid = threadIdx.x;
    const int u0  = wg8 * 8;
    const int wv  = tid >> 6, ln = tid & 63;
    const int bh  = wv >> 1, ch = wv & 1;
    const int fl  = ln & 15, fg = ln >> 4;

    s8v whi[16], wlo[16];
    const int col32 = ch * 16 + fl;
    const int gcol  = ((col32 >> 3) << 9) + u0 + (col32 & 7);  // gate*512 + unit
    #pragma unroll
    for (int it = 0; it < 16; ++it) {
        float v[8];
        #pragma unroll
        for (int j = 0; j < 8; ++j)
            v[j] = W[(size_t)(it * 32 + fg * 8 + j) * 2048 + gcol];
        UF H, L;
        #pragma unroll
        for (int q = 0; q < 4; ++q) {
            unsigned hp, lp;
            split2(v[2 * q], v[2 * q + 1], hp, lp);
            H.u[q] = hp; L.u[q] = lp;
        }
        whi[it] = H.s; wlo[it] = L.s;
    }
    const float bcol = bias[gcol];

    const int arow = bh * 16 + fl;                 // batch row this lane loads
    const float* xlane = x + (size_t)arow * TT * DD + fg * 8;
    const int crow = bh * 16 + fg * 4;             // C batch-row base (C[batch][gcol])

    for (int ii = 0; ii < 64; ++ii) {
        const int i = tcb * 64 + ii;
        const int t = t0 + i;
        f4v acc  = {0.f, 0.f, 0.f, 0.f};
        f4v accl = {0.f, 0.f, 0.f, 0.f};
        const float* xs = xlane + (size_t)t * DD;
        #pragma unroll
        for (int it = 0; it < 16; ++it) {
            float4 f0 = *(const float4*)(xs + it * 32);
            float4 f1 = *(const float4*)(xs + it * 32 + 4);
            UF H, L;
            unsigned hp, lp;
            split2(f0.x, f0.y, hp, lp); H.u[0] = hp; L.u[0] = lp;
            split2(f0.z, f0.w, hp, lp); H.u[1] = hp; L.u[1] = lp;
            split2(f1.x, f1.y, hp, lp); H.u[2] = hp; L.u[2] = lp;
            split2(f1.z, f1.w, hp, lp); H.u[3] = hp; L.u[3] = lp;
            acc  = __builtin_amdgcn_mfma_f32_16x16x32_bf16(H.s, whi[it], acc, 0, 0, 0);
            accl = __builtin_amdgcn_mfma_f32_16x16x32_bf16(L.s, whi[it], accl, 0, 0, 0);
            accl = __builtin_amdgcn_mfma_f32_16x16x32_bf16(H.s, wlo[it], accl, 0, 0, 0);
        }
        // transposed store: xg[i][gcol][batch], lane's 4 batches contiguous -> float4
        float4 st = {acc[0] + accl[0] + bcol, acc[1] + accl[1] + bcol,
                     acc[2] + accl[2] + bcol, acc[3] + accl[3] + bcol};
        *(float4*)(xg + (size_t)i * 65536 + (size_t)gcol * 32 + crow) = st;
    }
}

// Phase 2: persistent scan, 64 WGs x 4 autonomous waves, no LDS, no __syncthreads.
// C[gatecol][batch] = mfma(Wh_frag, h_frag): lane owns (batch=l&15(+bh*16),
// unit=u0+tile*4+(l>>4)) with acc[0..3] = i,f,g,o directly.
__global__ __launch_bounds__(NTHR, 1) void lstm_scan(
    const float* __restrict__ W,     // rows 512..1023 = Wh
    const float* __restrict__ xg,    // chunk-local [i][2048][32]
    float* __restrict__ out,
    unsigned* hhi,                   // cross-WG shared, packed bf16 pairs
    float* __restrict__ cbuf,
    unsigned* flags, int t0, int nt)
{
    const int wg  = blockIdx.x;
    const int tid = threadIdx.x;
    const int u0  = wg * 8;
    const int wv  = tid >> 6, ln = tid & 63;
    const int bh  = wv >> 1;         // batch half
    const int tile = wv & 1;         // unit quad
    const int lr  = ln & 15;
    const int lk  = ln >> 4;

    // A = Wh^T fragments, bf16 hi only: A row lr = lu*4+gate (lu=lr>>2, gate=lr&3)
    s8v whi[16];
    {
        const int wcol = (lr & 3) * 512 + u0 + tile * 4 + (lr >> 2);
        #pragma unroll
        for (int it = 0; it < 16; ++it) {
            UF H;
            #pragma unroll
            for (int q = 0; q < 4; ++q) {
                float a = W[(size_t)(512 + it * 32 + lk * 8 + 2 * q) * 2048 + wcol];
                float b = W[(size_t)(512 + it * 32 + lk * 8 + 2 * q + 1) * 2048 + wcol];
                H.u[q] = cvtpk(a, b);
            }
            whi[it] = H.s;
        }
    }

    const int batch = bh * 16 + lr;          // this lane's cell (batch, unit)
    const int uglob = u0 + tile * 4 + lk;
    float cst = cbuf[batch * HH + uglob];

    const int hb = batch * 256;              // u32 base: + it*16 + lk*4

    for (int i = 0; i < nt; ++i) {
        const int t = t0 + i;

        // xg loads first (no h dependency; hidden under the poll)
        const float* xi = xg + (size_t)i * 65536;
        float xgi = xi[(size_t)(0 * 512 + uglob) * 32 + batch];
        float xgf = xi[(size_t)(1 * 512 + uglob) * 32 + batch];
        float xgg = xi[(size_t)(2 * 512 + uglob) * 32 + batch];
        float xgo = xi[(size_t)(3 * 512 + uglob) * 32 + batch];

        // wait: all 256 waves published h_t (2 u64 atomic loads/lane cover all flags)
        if (t > 0) {
            const u64* f64 = (const u64*)flags;
            for (;;) {
                u64 a = __hip_atomic_load(&f64[ln * 2], __ATOMIC_RELAXED,
                                          __HIP_MEMORY_SCOPE_AGENT);
                u64 b = __hip_atomic_load(&f64[ln * 2 + 1], __ATOMIC_RELAXED,
                                          __HIP_MEMORY_SCOPE_AGENT);
                unsigned m0 = min((unsigned)a, (unsigned)(a >> 32));
                unsigned m1 = min((unsigned)b, (unsigned)(b >> 32));
                if (__all(min(m0, m1) >= (unsigned)t)) break;
            }
            __builtin_amdgcn_fence(__ATOMIC_ACQUIRE, "agent");
        }

        // h contribution: C[gatecol][batch], 16 MFMA (bf16 hi)
        f4v acc = {0.f, 0.f, 0.f, 0.f};
        {
            const unsigned* hh = hhi + (size_t)(t & 1) * (BB * HH / 2);
            #pragma unroll
            for (int it = 0; it < 16; ++it) {
                UF H;
                H.u = *(const u4v*)(hh + hb + it * 16 + lk * 4);
                acc = __builtin_amdgcn_mfma_f32_16x16x32_bf16(whi[it], H.s, acc, 0, 0, 0);
            }
        }

        // cell: acc[0..3] = i,f,g,o for (batch, uglob) — no LDS exchange
        float gi = xgi + acc[0];
        float gf = xgf + acc[1];
        float gg = xgg + acc[2];
        float go = xgo + acc[3];
        float si = 1.0f / (1.0f + __expf(-gi));
        float sf = 1.0f / (1.0f + __expf(-gf));
        float e2 = __expf(2.0f * fminf(fmaxf(gg, -15.f), 15.f));
        float tg = (e2 - 1.0f) / (e2 + 1.0f);
        float so = 1.0f / (1.0f + __expf(-go));
        cst = sf * cst + si * tg;
        float e2c = __expf(2.0f * fminf(fmaxf(cst, -15.f), 15.f));
        float h = so * (e2c - 1.0f) / (e2c + 1.0f);

        // publish h_{t+1}: unit pairs (lk even packs lk,lk+1), wave-local drain, flag
        {
            float hn = __shfl_down(h, 16);
            if ((lk & 1) == 0) {
                unsigned hp = cvtpk(h, hn);
                unsigned* dh = hhi + (size_t)((t + 1) & 1) * (BB * HH / 2);
                __hip_atomic_store(&dh[batch * 256 + (uglob >> 1)], hp,
                                   __ATOMIC_RELAXED, __HIP_MEMORY_SCOPE_AGENT);
            }
        }
        asm volatile("s_waitcnt vmcnt(0)" ::: "memory");
        __builtin_amdgcn_sched_barrier(0);
        if (ln == 0)
            __hip_atomic_store(&flags[wg * 4 + wv], (unsigned)(t + 1),
                               __ATOMIC_RELAXED, __HIP_MEMORY_SCOPE_AGENT);

        // outputs off the critical path
        out[(size_t)batch * TT * HH + (size_t)t * HH + uglob] = h;
        if (t == TT - 1) {
            size_t ho = (size_t)BB * TT * HH;
            out[ho + batch * HH + uglob] = h;
            out[ho + (size_t)BB * HH + batch * HH + uglob] = cst;
        }
    }

    cbuf[batch * HH + uglob] = cst;   // checkpoint c for next chunk
}

extern "C" void kernel_launch(void* const* d_in, const int* in_sizes, int n_in,
                              void* d_out, int out_size, void* d_ws, size_t ws_size,
                              hipStream_t stream) {
    const float* x  = nullptr;
    const float* W  = nullptr;
    const float* b  = nullptr;
    const float* h0 = nullptr;
    const float* c0 = nullptr;
    for (int i = 0; i < n_in; ++i) {
        int sz = in_sizes[i];
        if      (sz == BB * TT * DD)       x = (const float*)d_in[i];
        else if (sz == (DD + HH) * 4 * HH) W = (const float*)d_in[i];
        else if (sz == 4 * HH)             b = (const float*)d_in[i];
        else if (sz == BB * HH) { if (!h0) h0 = (const float*)d_in[i];
                                  else     c0 = (const float*)d_in[i]; }
    }
    float* out = (float*)d_out;

    char* base = (char*)d_ws;
    unsigned* hhi   = (unsigned*)(base);            // 2 x 8192 u32 = 64 KB
    float*    cbuf  = (float*)   (base + 65536);    // 64 KB
    unsigned* flags = (unsigned*)(base + 131072);   // 256 u32 (1 KB), pad to 4 KB
    float*    xg    = (float*)   (base + 135168);

    size_t avail = (ws_size > 135168) ? ws_size - 135168 : 0;
    size_t maxT  = avail / (BB * 2048 * sizeof(float));   // 262144 B per step
    int Tc = (int)((maxT / 64) * 64);
    if (Tc > TT) Tc = TT;
    if (Tc < 64) Tc = 64;

    lstm_init<<<64, NTHR, 0, stream>>>(h0, c0, hhi, cbuf, flags);

    for (int t0 = 0; t0 < TT; t0 += Tc) {
        int nt = (TT - t0 < Tc) ? (TT - t0) : Tc;
        gemm_xg<<<(nt / 64) * 64, NTHR, 0, stream>>>(x, W, b, xg, t0);
        lstm_scan<<<NWG, NTHR, 0, stream>>>(W, xg, out, hhi, cbuf, flags, t0, nt);
    }
}

// Round 14
// 20152.753 us; speedup vs baseline: 1.1060x; 1.0020x over previous
//
#include <hip/hip_runtime.h>

#define TT 2048
#define BB 32
#define DD 512
#define HH 512
#define NWG 64
#define NTHR 256

typedef short s8v __attribute__((ext_vector_type(8)));
typedef float f4v __attribute__((ext_vector_type(4)));
typedef unsigned u4v __attribute__((ext_vector_type(4)));
typedef unsigned long long u64;

union UF { u4v u; s8v s; };

__device__ __forceinline__ float asf(unsigned u) { return __uint_as_float(u); }

// v_cvt_pk_bf16_f32: D[15:0]=bf16(a) RNE, D[31:16]=bf16(b)
__device__ __forceinline__ unsigned cvtpk(float a, float b) {
    unsigned r;
    asm("v_cvt_pk_bf16_f32 %0, %1, %2" : "=v"(r) : "v"(a), "v"(b));
    return r;
}
__device__ __forceinline__ void split2(float a, float b, unsigned& hp, unsigned& lp) {
    hp = cvtpk(a, b);
    lp = cvtpk(a - asf(hp << 16), b - asf(hp & 0xFFFF0000u));
}

// ws (bytes): [0) hhi 2x32KB | [64K) cbuf 64K | [128K) flags 1K(+pad 4K) | [132K) xg chunk
__global__ void lstm_init(const float* __restrict__ h0, const float* __restrict__ c0,
                          unsigned* __restrict__ hhi, float* __restrict__ cbuf,
                          unsigned* __restrict__ flags) {
    int j = blockIdx.x * blockDim.x + threadIdx.x;   // 0..16383
    if (j < NWG * 4) flags[j] = 0u;                  // one flag per wave
    if (j < BB * HH / 2) hhi[j] = cvtpk(h0[2 * j], h0[2 * j + 1]);
    cbuf[j] = c0[j];
}

// Phase 1: xg[i][gatecol 2048][batch 32] = (x_t @ Wx + bias)^T   (hi/lo split GEMM)
__global__ __launch_bounds__(NTHR) void gemm_xg(
    const float* __restrict__ x, const float* __restrict__ W,
    const float* __restrict__ bias, float* __restrict__ xg, int t0)
{
    const int wg8 = blockIdx.x & 63;
    const int tcb = blockIdx.x >> 6;
    const int tid = threadIdx.x;
    const int u0  = wg8 * 8;
    const int wv  = tid >> 6, ln = tid & 63;
    const int bh  = wv >> 1, ch = wv & 1;
    const int fl  = ln & 15, fg = ln >> 4;

    s8v whi[16], wlo[16];
    const int col32 = ch * 16 + fl;
    const int gcol  = ((col32 >> 3) << 9) + u0 + (col32 & 7);  // gate*512 + unit
    #pragma unroll
    for (int it = 0; it < 16; ++it) {
        float v[8];
        #pragma unroll
        for (int j = 0; j < 8; ++j)
            v[j] = W[(size_t)(it * 32 + fg * 8 + j) * 2048 + gcol];
        UF H, L;
        #pragma unroll
        for (int q = 0; q < 4; ++q) {
            unsigned hp, lp;
            split2(v[2 * q], v[2 * q + 1], hp, lp);
            H.u[q] = hp; L.u[q] = lp;
        }
        whi[it] = H.s; wlo[it] = L.s;
    }
    const float bcol = bias[gcol];

    const int arow = bh * 16 + fl;                 // batch row this lane loads
    const float* xlane = x + (size_t)arow * TT * DD + fg * 8;
    const int crow = bh * 16 + fg * 4;             // C batch-row base (C[batch][gcol])

    for (int ii = 0; ii < 64; ++ii) {
        const int i = tcb * 64 + ii;
        const int t = t0 + i;
        f4v acc  = {0.f, 0.f, 0.f, 0.f};
        f4v accl = {0.f, 0.f, 0.f, 0.f};
        const float* xs = xlane + (size_t)t * DD;
        #pragma unroll
        for (int it = 0; it < 16; ++it) {
            float4 f0 = *(const float4*)(xs + it * 32);
            float4 f1 = *(const float4*)(xs + it * 32 + 4);
            UF H, L;
            unsigned hp, lp;
            split2(f0.x, f0.y, hp, lp); H.u[0] = hp; L.u[0] = lp;
            split2(f0.z, f0.w, hp, lp); H.u[1] = hp; L.u[1] = lp;
            split2(f1.x, f1.y, hp, lp); H.u[2] = hp; L.u[2] = lp;
            split2(f1.z, f1.w, hp, lp); H.u[3] = hp; L.u[3] = lp;
            acc  = __builtin_amdgcn_mfma_f32_16x16x32_bf16(H.s, whi[it], acc, 0, 0, 0);
            accl = __builtin_amdgcn_mfma_f32_16x16x32_bf16(L.s, whi[it], accl, 0, 0, 0);
            accl = __builtin_amdgcn_mfma_f32_16x16x32_bf16(H.s, wlo[it], accl, 0, 0, 0);
        }
        // transposed store: xg[i][gcol][batch], lane's 4 batches contiguous -> float4
        float4 st = {acc[0] + accl[0] + bcol, acc[1] + accl[1] + bcol,
                     acc[2] + accl[2] + bcol, acc[3] + accl[3] + bcol};
        *(float4*)(xg + (size_t)i * 65536 + (size_t)gcol * 32 + crow) = st;
    }
}

// Phase 2: persistent scan, 64 WGs x 4 autonomous waves, no LDS, no __syncthreads.
// C[gatecol][batch] = mfma(Wh_frag, h_frag): lane owns (batch=l&15(+bh*16),
// unit=u0+tile*4+(l>>4)) with acc[0..3] = i,f,g,o directly.
__global__ __launch_bounds__(NTHR, 1) void lstm_scan(
    const float* __restrict__ W,     // rows 512..1023 = Wh
    const float* __restrict__ xg,    // chunk-local [i][2048][32]
    float* __restrict__ out,
    unsigned* hhi,                   // cross-WG shared, packed bf16 pairs
    float* __restrict__ cbuf,
    unsigned* flags, int t0, int nt)
{
    const int wg  = blockIdx.x;
    const int tid = threadIdx.x;
    const int u0  = wg * 8;
    const int wv  = tid >> 6, ln = tid & 63;
    const int bh  = wv >> 1;         // batch half
    const int tile = wv & 1;         // unit quad
    const int lr  = ln & 15;
    const int lk  = ln >> 4;

    // A = Wh^T fragments, bf16 hi only: A row lr = lu*4+gate (lu=lr>>2, gate=lr&3)
    s8v whi[16];
    {
        const int wcol = (lr & 3) * 512 + u0 + tile * 4 + (lr >> 2);
        #pragma unroll
        for (int it = 0; it < 16; ++it) {
            UF H;
            #pragma unroll
            for (int q = 0; q < 4; ++q) {
                float a = W[(size_t)(512 + it * 32 + lk * 8 + 2 * q) * 2048 + wcol];
                float b = W[(size_t)(512 + it * 32 + lk * 8 + 2 * q + 1) * 2048 + wcol];
                H.u[q] = cvtpk(a, b);
            }
            whi[it] = H.s;
        }
    }

    const int batch = bh * 16 + lr;          // this lane's cell (batch, unit)
    const int uglob = u0 + tile * 4 + lk;
    float cst = cbuf[batch * HH + uglob];

    const int hb = batch * 256;              // u32 base: + it*16 + lk*4

    for (int i = 0; i < nt; ++i) {
        const int t = t0 + i;

        // xg loads first (no h dependency; hidden under the poll)
        const float* xi = xg + (size_t)i * 65536;
        float xgi = xi[(size_t)(0 * 512 + uglob) * 32 + batch];
        float xgf = xi[(size_t)(1 * 512 + uglob) * 32 + batch];
        float xgg = xi[(size_t)(2 * 512 + uglob) * 32 + batch];
        float xgo = xi[(size_t)(3 * 512 + uglob) * 32 + batch];

        // wait: all 256 waves published h_t (2 u64 atomic loads/lane cover all flags)
        if (t > 0) {
            const u64* f64 = (const u64*)flags;
            for (;;) {
                u64 a = __hip_atomic_load(&f64[ln * 2], __ATOMIC_RELAXED,
                                          __HIP_MEMORY_SCOPE_AGENT);
                u64 b = __hip_atomic_load(&f64[ln * 2 + 1], __ATOMIC_RELAXED,
                                          __HIP_MEMORY_SCOPE_AGENT);
                unsigned m0 = min((unsigned)a, (unsigned)(a >> 32));
                unsigned m1 = min((unsigned)b, (unsigned)(b >> 32));
                if (__all(min(m0, m1) >= (unsigned)t)) break;
            }
            __builtin_amdgcn_fence(__ATOMIC_ACQUIRE, "agent");
        }

        // h contribution: C[gatecol][batch], 16 MFMA (bf16 hi)
        f4v acc = {0.f, 0.f, 0.f, 0.f};
        {
            const unsigned* hh = hhi + (size_t)(t & 1) * (BB * HH / 2);
            #pragma unroll
            for (int it = 0; it < 16; ++it) {
                UF H;
                H.u = *(const u4v*)(hh + hb + it * 16 + lk * 4);
                acc = __builtin_amdgcn_mfma_f32_16x16x32_bf16(whi[it], H.s, acc, 0, 0, 0);
            }
        }

        // cell: acc[0..3] = i,f,g,o for (batch, uglob) — no LDS exchange
        float gi = xgi + acc[0];
        float gf = xgf + acc[1];
        float gg = xgg + acc[2];
        float go = xgo + acc[3];
        float si = 1.0f / (1.0f + __expf(-gi));
        float sf = 1.0f / (1.0f + __expf(-gf));
        float e2 = __expf(2.0f * fminf(fmaxf(gg, -15.f), 15.f));
        float tg = (e2 - 1.0f) / (e2 + 1.0f);
        float so = 1.0f / (1.0f + __expf(-go));
        cst = sf * cst + si * tg;
        float e2c = __expf(2.0f * fminf(fmaxf(cst, -15.f), 15.f));
        float h = so * (e2c - 1.0f) / (e2c + 1.0f);

        // publish h_{t+1}: unit pairs (lk even packs lk,lk+1), wave-local drain, flag
        {
            float hn = __shfl_down(h, 16);
            if ((lk & 1) == 0) {
                unsigned hp = cvtpk(h, hn);
                unsigned* dh = hhi + (size_t)((t + 1) & 1) * (BB * HH / 2);
                __hip_atomic_store(&dh[batch * 256 + (uglob >> 1)], hp,
                                   __ATOMIC_RELAXED, __HIP_MEMORY_SCOPE_AGENT);
            }
        }
        asm volatile("s_waitcnt vmcnt(0)" ::: "memory");
        __builtin_amdgcn_sched_barrier(0);
        if (ln == 0)
            __hip_atomic_store(&flags[wg * 4 + wv], (unsigned)(t + 1),
                               __ATOMIC_RELAXED, __HIP_MEMORY_SCOPE_AGENT);

        // outputs off the critical path
        out[(size_t)batch * TT * HH + (size_t)t * HH + uglob] = h;
        if (t == TT - 1) {
            size_t ho = (size_t)BB * TT * HH;
            out[ho + batch * HH + uglob] = h;
            out[ho + (size_t)BB * HH + batch * HH + uglob] = cst;
        }
    }

    cbuf[batch * HH + uglob] = cst;   // checkpoint c for next chunk
}

extern "C" void kernel_launch(void* const* d_in, const int* in_sizes, int n_in,
                              void* d_out, int out_size, void* d_ws, size_t ws_size,
                              hipStream_t stream) {
    const float* x  = nullptr;
    const float* W  = nullptr;
    const float* b  = nullptr;
    const float* h0 = nullptr;
    const float* c0 = nullptr;
    for (int i = 0; i < n_in; ++i) {
        int sz = in_sizes[i];
        if      (sz == BB * TT * DD)       x = (const float*)d_in[i];
        else if (sz == (DD + HH) * 4 * HH) W = (const float*)d_in[i];
        else if (sz == 4 * HH)             b = (const float*)d_in[i];
        else if (sz == BB * HH) { if (!h0) h0 = (const float*)d_in[i];
                                  else     c0 = (const float*)d_in[i]; }
    }
    float* out = (float*)d_out;

    char* base = (char*)d_ws;
    unsigned* hhi   = (unsigned*)(base);            // 2 x 8192 u32 = 64 KB
    float*    cbuf  = (float*)   (base + 65536);    // 64 KB
    unsigned* flags = (unsigned*)(base + 131072);   // 256 u32 (1 KB), pad to 4 KB
    float*    xg    = (float*)   (base + 135168);

    size_t avail = (ws_size > 135168) ? ws_size - 135168 : 0;
    size_t maxT  = avail / (BB * 2048 * sizeof(float));   // 262144 B per step
    int Tc = (int)((maxT / 64) * 64);
    if (Tc > TT) Tc = TT;
    if (Tc < 64) Tc = 64;

    lstm_init<<<64, NTHR, 0, stream>>>(h0, c0, hhi, cbuf, flags);

    for (int t0 = 0; t0 < TT; t0 += Tc) {
        int nt = (TT - t0 < Tc) ? (TT - t0) : Tc;
        gemm_xg<<<(nt / 64) * 64, NTHR, 0, stream>>>(x, W, b, xg, t0);
        lstm_scan<<<NWG, NTHR, 0, stream>>>(W, xg, out, hhi, cbuf, flags, t0, nt);
    }
}

// Round 16
// 17422.372 us; speedup vs baseline: 1.2794x; 1.1567x over previous
//
#include <hip/hip_runtime.h>

#define TT 2048
#define BB 32
#define DD 512
#define HH 512
#define NWG 64
#define NTHR 256
#define POISON 0x7FC07FC0u

typedef short s8v __attribute__((ext_vector_type(8)));
typedef float f4v __attribute__((ext_vector_type(4)));
typedef unsigned u4v __attribute__((ext_vector_type(4)));

union UF { u4v u; s8v s; };

__device__ __forceinline__ float asf(unsigned u) { return __uint_as_float(u); }

__device__ __forceinline__ unsigned cvtpk(float a, float b) {
    unsigned r;
    asm("v_cvt_pk_bf16_f32 %0, %1, %2" : "=v"(r) : "v"(a), "v"(b));
    return r;
}
__device__ __forceinline__ void split2(float a, float b, unsigned& hp, unsigned& lp) {
    hp = cvtpk(a, b);
    lp = cvtpk(a - asf(hp << 16), b - asf(hp & 0xFFFF0000u));
}

// ws (bytes): [0) hbuf 3 x 32KB (3-rotation packed bf16-pair h) | [96K) cbuf 64K | [160K) xg chunk
__global__ void lstm_init(const float* __restrict__ h0, const float* __restrict__ c0,
                          unsigned* __restrict__ hbuf, float* __restrict__ cbuf) {
    int j = blockIdx.x * blockDim.x + threadIdx.x;   // 0..16383
    if (j < BB * HH / 2) {
        hbuf[j] = cvtpk(h0[2 * j], h0[2 * j + 1]);   // buf0 = h_0
        hbuf[8192 + j]  = POISON;                     // buf1, buf2 poisoned
        hbuf[16384 + j] = POISON;
    }
    cbuf[j] = c0[j];
}

// Phase 1: xg[i][gatecol 2048][batch 32] = (x_t @ Wx + bias)^T   (hi/lo split GEMM)
__global__ __launch_bounds__(NTHR) void gemm_xg(
    const float* __restrict__ x, const float* __restrict__ W,
    const float* __restrict__ bias, float* __restrict__ xg, int t0, int nt)
{
    const int wg8 = blockIdx.x & 63;
    const int tq  = (blockIdx.x >> 6) & 3;
    const int tb  = blockIdx.x >> 8;
    const int tid = threadIdx.x;
    const int u0  = wg8 * 8;
    const int wv  = tid >> 6, ln = tid & 63;
    const int bh  = wv >> 1, ch = wv & 1;
    const int fl  = ln & 15, fg = ln >> 4;

    s8v whi[16], wlo[16];
    const int col32 = ch * 16 + fl;
    const int gcol  = ((col32 >> 3) << 9) + u0 + (col32 & 7);  // gate*512 + unit
    #pragma unroll
    for (int it = 0; it < 16; ++it) {
        float v[8];
        #pragma unroll
        for (int j = 0; j < 8; ++j)
            v[j] = W[(size_t)(it * 32 + fg * 8 + j) * 2048 + gcol];
        UF H, L;
        #pragma unroll
        for (int q = 0; q < 4; ++q) {
            unsigned hp, lp;
            split2(v[2 * q], v[2 * q + 1], hp, lp);
            H.u[q] = hp; L.u[q] = lp;
        }
        whi[it] = H.s; wlo[it] = L.s;
    }
    const float bcol = bias[gcol];

    const int arow = bh * 16 + fl;
    const float* xlane = x + (size_t)arow * TT * DD + fg * 8;
    const int crow = bh * 16 + fg * 4;

    for (int ii = 0; ii < 16; ++ii) {
        const int i = tb * 64 + tq * 16 + ii;
        if (i >= nt) break;
        const int t = t0 + i;
        f4v acc  = {0.f, 0.f, 0.f, 0.f};
        f4v accl = {0.f, 0.f, 0.f, 0.f};
        const float* xs = xlane + (size_t)t * DD;
        #pragma unroll
        for (int it = 0; it < 16; ++it) {
            float4 f0 = *(const float4*)(xs + it * 32);
            float4 f1 = *(const float4*)(xs + it * 32 + 4);
            UF H, L;
            unsigned hp, lp;
            split2(f0.x, f0.y, hp, lp); H.u[0] = hp; L.u[0] = lp;
            split2(f0.z, f0.w, hp, lp); H.u[1] = hp; L.u[1] = lp;
            split2(f1.x, f1.y, hp, lp); H.u[2] = hp; L.u[2] = lp;
            split2(f1.z, f1.w, hp, lp); H.u[3] = hp; L.u[3] = lp;
            acc  = __builtin_amdgcn_mfma_f32_16x16x32_bf16(H.s, whi[it], acc, 0, 0, 0);
            accl = __builtin_amdgcn_mfma_f32_16x16x32_bf16(L.s, whi[it], accl, 0, 0, 0);
            accl = __builtin_amdgcn_mfma_f32_16x16x32_bf16(H.s, wlo[it], accl, 0, 0, 0);
        }
        float4 st = {acc[0] + accl[0] + bcol, acc[1] + accl[1] + bcol,
                     acc[2] + accl[2] + bcol, acc[3] + accl[3] + bcol};
        *(float4*)(xg + (size_t)i * 65536 + (size_t)gcol * 32 + crow) = st;
    }
}

// Phase 2: flagless scan — 3-buffer rotation, poison-sentinel data polling.
// r14-verified transposed recurrence: acc[0..3] = i,f,g,o of (batch, uglob).
__global__ __launch_bounds__(NTHR, 1) void lstm_scan(
    const float* __restrict__ W,     // rows 512..1023 = Wh
    const float* __restrict__ xg,    // chunk-local [i][2048][32]
    float* __restrict__ out,
    unsigned* hbuf,                  // 3 x 8192 u32, cross-WG shared
    float* __restrict__ cbuf,
    int t0, int nt)
{
    const int wg  = blockIdx.x;
    const int tid = threadIdx.x;
    const int u0  = wg * 8;
    const int wv  = tid >> 6, ln = tid & 63;
    const int bh  = wv >> 1;         // batch half
    const int tile = wv & 1;         // unit quad
    const int lr  = ln & 15;
    const int lk  = ln >> 4;

    // A = Wh^T fragments, bf16 hi: A row lr -> gatecol = (lr&3)*512 + u0 + tile*4 + (lr>>2)
    s8v whi[16];
    {
        const int wcol = (lr & 3) * 512 + u0 + tile * 4 + (lr >> 2);
        #pragma unroll
        for (int it = 0; it < 16; ++it) {
            UF H;
            #pragma unroll
            for (int q = 0; q < 4; ++q) {
                float a = W[(size_t)(512 + it * 32 + lk * 8 + 2 * q) * 2048 + wcol];
                float b = W[(size_t)(512 + it * 32 + lk * 8 + 2 * q + 1) * 2048 + wcol];
                H.u[q] = cvtpk(a, b);
            }
            whi[it] = H.s;
        }
    }

    const int batch = bh * 16 + lr;          // this lane's cell (batch, unit)
    const int uglob = u0 + tile * 4 + lk;
    float cst = cbuf[batch * HH + uglob];

    const int hb   = batch * 256;            // u32 base: + it*16 + lk*4
    const int slot = batch * 256 + (uglob >> 1);

    int rot = t0 % 3;                        // buffer index of h_t

    for (int i = 0; i < nt; ++i) {
        const int t = t0 + i;
        const int rotP = (rot == 2) ? 0 : rot + 1;   // h_{t+1} target
        const int rotZ = (rotP == 2) ? 0 : rotP + 1; // dead buffer (held h_{t-1})

        // xg prefetch (plain loads; drained by the first fence, values kept in regs)
        const float* xi = xg + (size_t)i * 65536;
        float xgi = xi[(size_t)(0 * 512 + uglob) * 32 + batch];
        float xgf = xi[(size_t)(1 * 512 + uglob) * 32 + batch];
        float xgg = xi[(size_t)(2 * 512 + uglob) * 32 + batch];
        float xgo = xi[(size_t)(3 * 512 + uglob) * 32 + batch];

        // ---- gather h_t by data-polling (fence + reload invalid fragments)
        const unsigned* bufR = hbuf + (size_t)rot * 8192;
        u4v f[16];
        unsigned vm = 0;
        do {
            __builtin_amdgcn_fence(__ATOMIC_ACQUIRE, "agent");
            #pragma unroll
            for (int it = 0; it < 16; ++it) {
                if (!(vm & (1u << it))) {
                    u4v v = *(const u4v*)(bufR + hb + it * 16 + lk * 4);
                    if (v[0] != POISON && v[1] != POISON &&
                        v[2] != POISON && v[3] != POISON) {
                        f[it] = v; vm |= 1u << it;
                    }
                }
            }
        } while (vm != 0xFFFFu);

        // ---- poison the dead buffer (h_{t-1}, fully consumed) for reuse at t+2
        unsigned* bufZ = hbuf + (size_t)rotZ * 8192;
        if ((lk & 1) == 0)
            __hip_atomic_store(&bufZ[slot], POISON,
                               __ATOMIC_RELAXED, __HIP_MEMORY_SCOPE_AGENT);

        // ---- recurrence MFMA: C[gatecol][batch], bf16-hi
        f4v acc = {0.f, 0.f, 0.f, 0.f};
        #pragma unroll
        for (int it = 0; it < 16; ++it) {
            UF F; F.u = f[it];
            acc = __builtin_amdgcn_mfma_f32_16x16x32_bf16(whi[it], F.s, acc, 0, 0, 0);
        }

        // ---- cell
        float gi = xgi + acc[0];
        float gf = xgf + acc[1];
        float gg = xgg + acc[2];
        float go = xgo + acc[3];
        float si = 1.0f / (1.0f + __expf(-gi));
        float sf = 1.0f / (1.0f + __expf(-gf));
        float e2 = __expf(2.0f * fminf(fmaxf(gg, -15.f), 15.f));
        float tg = (e2 - 1.0f) / (e2 + 1.0f);
        float so = 1.0f / (1.0f + __expf(-go));
        cst = sf * cst + si * tg;
        float e2c = __expf(2.0f * fminf(fmaxf(cst, -15.f), 15.f));
        float h = so * (e2c - 1.0f) / (e2c + 1.0f);

        // ---- ensure poison committed before our publish can be observed
        asm volatile("s_waitcnt vmcnt(0)" ::: "memory");
        __builtin_amdgcn_sched_barrier(0);

        // ---- publish h_{t+1}
        {
            float hn = __shfl_down(h, 16);
            if ((lk & 1) == 0) {
                unsigned* bufP = hbuf + (size_t)rotP * 8192;
                __hip_atomic_store(&bufP[slot], cvtpk(h, hn),
                                   __ATOMIC_RELAXED, __HIP_MEMORY_SCOPE_AGENT);
            }
        }

        // ---- outputs off the critical path
        out[(size_t)batch * TT * HH + (size_t)t * HH + uglob] = h;
        if (t == TT - 1) {
            size_t ho = (size_t)BB * TT * HH;
            out[ho + batch * HH + uglob] = h;
            out[ho + (size_t)BB * HH + batch * HH + uglob] = cst;
        }

        rot = rotP;
    }

    cbuf[batch * HH + uglob] = cst;   // checkpoint c for next chunk
}

extern "C" void kernel_launch(void* const* d_in, const int* in_sizes, int n_in,
                              void* d_out, int out_size, void* d_ws, size_t ws_size,
                              hipStream_t stream) {
    const float* x  = nullptr;
    const float* W  = nullptr;
    const float* b  = nullptr;
    const float* h0 = nullptr;
    const float* c0 = nullptr;
    for (int i = 0; i < n_in; ++i) {
        int sz = in_sizes[i];
        if      (sz == BB * TT * DD)       x = (const float*)d_in[i];
        else if (sz == (DD + HH) * 4 * HH) W = (const float*)d_in[i];
        else if (sz == 4 * HH)             b = (const float*)d_in[i];
        else if (sz == BB * HH) { if (!h0) h0 = (const float*)d_in[i];
                                  else     c0 = (const float*)d_in[i]; }
    }
    float* out = (float*)d_out;

    char* base = (char*)d_ws;
    unsigned* hbuf = (unsigned*)(base);             // 3 x 8192 u32 = 96 KB
    float*    cbuf = (float*)   (base + 98304);     // 64 KB
    float*    xg   = (float*)   (base + 163840);

    size_t avail = (ws_size > 163840) ? ws_size - 163840 : 0;
    long maxT = (long)(avail / 262144);             // 256 KB per step
    int Tc = (maxT > TT) ? TT : (int)maxT;
    if (Tc < 32) Tc = 32;

    lstm_init<<<64, NTHR, 0, stream>>>(h0, c0, hbuf, cbuf);

    for (int t0 = 0; t0 < TT; t0 += Tc) {
        int nt = (TT - t0 < Tc) ? (TT - t0) : Tc;
        int tblocks = (nt + 63) / 64;
        gemm_xg<<<tblocks * 256, NTHR, 0, stream>>>(x, W, b, xg, t0, nt);
        lstm_scan<<<NWG, NTHR, 0, stream>>>(W, xg, out, hbuf, cbuf, t0, nt);
    }
}